// Round 1
// baseline (484.372 us; speedup 1.0000x reference)
//
#include <hip/hip_runtime.h>
#include <hip/hip_bf16.h>
#include <cstdint>
#include <cstddef>

#define NE 16
#define NB 32768
#define LATENT 128
#define HID 64
#define CLASSES 10
#define BPE 32          // blocks per expert
#define TPB 256         // threads per block (4 waves)

// ---------------------------------------------------------------------------
// Probe: decide whether mask is stored as bytes (bool) or 4-byte words
// (int32/float32). Columns b ≡ 1 (mod 4): for byte-bool data every column has
// exactly one nonzero byte; for int32/float32 0/1 data those byte offsets are
// always 0x00. flag=1 -> byte mode, flag=0 -> word mode.
// ---------------------------------------------------------------------------
__global__ void probe_kernel(const unsigned char* __restrict__ mask_bytes,
                             int* __restrict__ flag) {
    int tid = threadIdx.x;
    if (tid < 32) {
        int b = 1 + 4 * tid;            // b = 1,5,9,...,125  (all ≡1 mod 4)
        int nz = 0;
        for (int e = 0; e < NE; ++e) nz |= mask_bytes[(size_t)e * NB + b];
        if (nz) atomicOr(flag, 1);
    }
}

// ---------------------------------------------------------------------------
// Assign: find each token's expert, bucket token ids per expert.
// ---------------------------------------------------------------------------
__global__ void assign_kernel(const void* __restrict__ mask,
                              const int* __restrict__ flag,
                              int* __restrict__ counts,
                              unsigned short* __restrict__ lists) {
    int b = blockIdx.x * blockDim.x + threadIdx.x;
    if (b >= NB) return;
    int mode = *flag;                   // uniform
    int myE = 0;
    if (mode) {
        const unsigned char* m = (const unsigned char*)mask;
        for (int e = 0; e < NE; ++e)
            if (m[(size_t)e * NB + b]) { myE = e; break; }
    } else {
        const int* m = (const int*)mask;   // also correct for float32 0.0/1.0
        for (int e = 0; e < NE; ++e)
            if (m[(size_t)e * NB + b] != 0) { myE = e; break; }
    }
    int pos = atomicAdd(&counts[myE], 1);
    lists[myE * NB + pos] = (unsigned short)b;
}

// ---------------------------------------------------------------------------
// Per-expert MLP. Each block: one expert, weights staged in LDS (~52 KB).
// Each wave processes 4 tokens per iteration; lane = output channel.
// ---------------------------------------------------------------------------
__global__ __launch_bounds__(TPB, 2) void expert_kernel(
    const float* __restrict__ latent,
    const float* __restrict__ W1, const float* __restrict__ b1,
    const float* __restrict__ W2, const float* __restrict__ b2,
    const float* __restrict__ W3, const float* __restrict__ b3,
    const int* __restrict__ counts,
    const unsigned short* __restrict__ lists,
    float* __restrict__ out)
{
    __shared__ float sW1[LATENT * HID];          // 32 KB, [l][j]
    __shared__ float sW2[HID * HID];             // 16 KB, [h][j]
    __shared__ float sW3[HID * CLASSES + 8];     // 2.5 KB (+pad for c=10..15 reads)
    __shared__ float sB1[HID], sB2[HID], sB3[16];
    __shared__ float sX[4][4][LATENT];           // [wave][t][128], 8 KB; reused for h1,h2

    const int e    = blockIdx.x / BPE;
    const int blk  = blockIdx.x % BPE;
    const int tid  = threadIdx.x;
    const int wave = tid >> 6;
    const int lane = tid & 63;

    // ---- stage weights (float4) ----
    {
        const float* g = W1 + (size_t)e * LATENT * HID;
        for (int i = tid * 4; i < LATENT * HID; i += TPB * 4)
            *(float4*)&sW1[i] = *(const float4*)&g[i];
        g = W2 + (size_t)e * HID * HID;
        for (int i = tid * 4; i < HID * HID; i += TPB * 4)
            *(float4*)&sW2[i] = *(const float4*)&g[i];
        g = W3 + (size_t)e * HID * CLASSES;
        for (int i = tid * 4; i < HID * CLASSES; i += TPB * 4)
            *(float4*)&sW3[i] = *(const float4*)&g[i];
        if (tid < HID) {
            sB1[tid] = b1[e * HID + tid];
            sB2[tid] = b2[e * HID + tid];
        }
        if (tid < 16) sB3[tid] = (tid < CLASSES) ? b3[e * CLASSES + tid] : 0.f;
    }
    __syncthreads();

    const int cnt = counts[e];
    if (cnt == 0) return;                         // block-uniform
    const int ntiles = (cnt + 15) >> 4;
    const unsigned short* mylist = lists + e * NB;

    for (int tile = blk; tile < ntiles; tile += BPE) {
        const int base = tile * 16;

        // ---- stage 16 tokens x 128 floats of latent ----
        {
            int s = tid >> 4, p = tid & 15;       // token slot, 8-float chunk
            int idx = base + s;
            int tok = mylist[idx < cnt ? idx : 0];
            const float4* src =
                (const float4*)(latent + ((size_t)e * NB + tok) * LATENT + p * 8);
            float4 v0 = src[0], v1 = src[1];
            float4* dst = (float4*)&sX[s >> 2][s & 3][p * 8];
            dst[0] = v0; dst[1] = v1;
        }
        __syncthreads();

        // ---- layer 1: [4 tok] x [128 -> 64], lane = channel j ----
        float a0 = sB1[lane], a1 = a0, a2 = a0, a3 = a0;
        for (int l = 0; l < LATENT; l += 4) {
            float w0 = sW1[(l + 0) * HID + lane];
            float w1 = sW1[(l + 1) * HID + lane];
            float w2 = sW1[(l + 2) * HID + lane];
            float w3 = sW1[(l + 3) * HID + lane];
            float4 x0 = *(const float4*)&sX[wave][0][l];
            float4 x1 = *(const float4*)&sX[wave][1][l];
            float4 x2 = *(const float4*)&sX[wave][2][l];
            float4 x3 = *(const float4*)&sX[wave][3][l];
            a0 += x0.x * w0 + x0.y * w1 + x0.z * w2 + x0.w * w3;
            a1 += x1.x * w0 + x1.y * w1 + x1.z * w2 + x1.w * w3;
            a2 += x2.x * w0 + x2.y * w1 + x2.z * w2 + x2.w * w3;
            a3 += x3.x * w0 + x3.y * w1 + x3.z * w2 + x3.w * w3;
        }
        a0 = fmaxf(a0, 0.f); a1 = fmaxf(a1, 0.f);
        a2 = fmaxf(a2, 0.f); a3 = fmaxf(a3, 0.f);
        // write h1 into own wave's sX rows (lockstep: all reads above are done)
        sX[wave][0][lane] = a0; sX[wave][1][lane] = a1;
        sX[wave][2][lane] = a2; sX[wave][3][lane] = a3;
        __syncthreads();

        // ---- layer 2: [4 tok] x [64 -> 64] ----
        float c0 = sB2[lane], c1 = c0, c2 = c0, c3 = c0;
        for (int h = 0; h < HID; h += 4) {
            float w0 = sW2[(h + 0) * HID + lane];
            float w1 = sW2[(h + 1) * HID + lane];
            float w2 = sW2[(h + 2) * HID + lane];
            float w3 = sW2[(h + 3) * HID + lane];
            float4 x0 = *(const float4*)&sX[wave][0][h];
            float4 x1 = *(const float4*)&sX[wave][1][h];
            float4 x2 = *(const float4*)&sX[wave][2][h];
            float4 x3 = *(const float4*)&sX[wave][3][h];
            c0 += x0.x * w0 + x0.y * w1 + x0.z * w2 + x0.w * w3;
            c1 += x1.x * w0 + x1.y * w1 + x1.z * w2 + x1.w * w3;
            c2 += x2.x * w0 + x2.y * w1 + x2.z * w2 + x2.w * w3;
            c3 += x3.x * w0 + x3.y * w1 + x3.z * w2 + x3.w * w3;
        }
        c0 = fmaxf(c0, 0.f); c1 = fmaxf(c1, 0.f);
        c2 = fmaxf(c2, 0.f); c3 = fmaxf(c3, 0.f);
        sX[wave][0][lane] = c0; sX[wave][1][lane] = c1;
        sX[wave][2][lane] = c2; sX[wave][3][lane] = c3;
        __syncthreads();

        // ---- layer 3: [4 tok] x [64 -> 10]; lane = (t, c) = (lane>>4, lane&15) ----
        {
            int t = lane >> 4, c = lane & 15;
            float acc = sB3[c];
            for (int h = 0; h < HID; ++h)
                acc += sX[wave][t][h] * sW3[h * CLASSES + c];
            int slot = base + wave * 4 + t;
            if (c < CLASSES && slot < cnt) {
                int tok = mylist[slot];
                out[(size_t)tok * CLASSES + c] = acc;
            }
        }
        __syncthreads();   // protect sX before next iteration's staging
    }
}

extern "C" void kernel_launch(void* const* d_in, const int* in_sizes, int n_in,
                              void* d_out, int out_size, void* d_ws, size_t ws_size,
                              hipStream_t stream) {
    // inputs: 0=x(unused), 1=mask, 2=latent, 3=W1, 4=b1, 5=W2, 6=b2, 7=W3, 8=b3
    const void*  mask   = d_in[1];
    const float* latent = (const float*)d_in[2];
    const float* W1 = (const float*)d_in[3];
    const float* b1 = (const float*)d_in[4];
    const float* W2 = (const float*)d_in[5];
    const float* b2 = (const float*)d_in[6];
    const float* W3 = (const float*)d_in[7];
    const float* b3 = (const float*)d_in[8];
    float* out = (float*)d_out;

    int* flag   = (int*)d_ws;                                   // 4 B
    int* counts = (int*)((char*)d_ws + 64);                     // 64 B
    unsigned short* lists = (unsigned short*)((char*)d_ws + 128); // 1 MB

    hipMemsetAsync(d_ws, 0, 128, stream);
    probe_kernel<<<1, 64, 0, stream>>>((const unsigned char*)mask, flag);
    assign_kernel<<<NB / 256, 256, 0, stream>>>(mask, flag, counts, lists);
    expert_kernel<<<NE * BPE, TPB, 0, stream>>>(latent, W1, b1, W2, b2, W3, b3,
                                                counts, lists, out);
}